// Round 3
// baseline (145.569 us; speedup 1.0000x reference)
//
#include <hip/hip_runtime.h>
#include <hip/hip_bf16.h>
#include <stdint.h>

typedef unsigned short u16;
typedef __attribute__((ext_vector_type(8))) short short8;
typedef __attribute__((ext_vector_type(8))) __bf16 bf16x8;
typedef __attribute__((ext_vector_type(4))) float f32x4;

constexpr int Bc  = 4;
constexpr int Tc  = 2048;
constexpr int Dc  = 768;
constexpr int Hc  = 12;
constexpr int WINc = 128;

static __device__ __forceinline__ u16 f2bf(float f) {
  union { float f; uint32_t u; } v; v.f = f;
  uint32_t u = v.u;
  return (u16)((u + 0x7fffu + ((u >> 16) & 1u)) >> 16);
}

static __device__ __forceinline__ f32x4 mfma16x16x32(bf16x8 a, bf16x8 b, f32x4 c) {
  return __builtin_amdgcn_mfma_f32_16x16x32_bf16(a, b, c, 0, 0, 0);
}

#define GLOAD_LDS16(gsrc, ldst)                                                \
  __builtin_amdgcn_global_load_lds(                                            \
      (const __attribute__((address_space(1))) void*)(gsrc),                   \
      (__attribute__((address_space(3))) void*)(ldst), 16, 0, 0)

// ---------------------------------------------------------------- cvt x -> bf16
__global__ __launch_bounds__(256) void cvt_f32_to_bf16(const float* __restrict__ in,
                                                       u16* __restrict__ out) {
  const int i = blockIdx.x * 256 + threadIdx.x;
  const float4 f = ((const float4*)in)[i];
  union { u16 h[4]; uint2 u; } pk;
  pk.h[0] = f2bf(f.x); pk.h[1] = f2bf(f.y); pk.h[2] = f2bf(f.z); pk.h[3] = f2bf(f.w);
  ((uint2*)out)[i] = pk.u;
}

// ------------------------------------------- W [R][C] f32  ->  WT [C][R] bf16
__global__ __launch_bounds__(256) void transpose_cvt(const float* __restrict__ W,
                                                     u16* __restrict__ WT,
                                                     int R, int C) {
  __shared__ float tile[64][65];
  const int t  = threadIdx.x;
  const int c0 = blockIdx.x * 64, r0 = blockIdx.y * 64;
#pragma unroll
  for (int i = 0; i < 16; ++i) {
    const int e = i * 256 + t;
    const int r = e >> 6, c = e & 63;
    tile[r][c] = W[(size_t)(r0 + r) * C + c0 + c];
  }
  __syncthreads();
#pragma unroll
  for (int i = 0; i < 16; ++i) {
    const int e = i * 256 + t;
    const int r = e >> 6, c = e & 63;
    WT[(size_t)(c0 + r) * R + r0 + c] = f2bf(tile[c][r]);
  }
}

// ---------------------------------------------------------------- GEMM  C = A * B^T
// 2-phase double-buffered pipeline: issue next K-tile's global_load_lds BEFORE
// compute of current tile; single barrier per K-step (T3-minimum recipe).
// EPI==0: split columns into q/k (row-major [bh][t][64]) and V TRANSPOSED
//         ([bh][d=64][T=2048]) so attention can consume V without LDS transpose.
// EPI==1: write f32 to out [M][768].
template <int EPI>
__global__ __launch_bounds__(256) void gemm_bt(const u16* __restrict__ A,
                                               const u16* __restrict__ Bt,
                                               u16* __restrict__ q_ws,
                                               u16* __restrict__ k_ws,
                                               u16* __restrict__ v_ws,
                                               float* __restrict__ fout) {
  __shared__ u16 As[2][128][32];   // 8 KB per buf
  __shared__ u16 Bs[2][128][32];
  const int t  = threadIdx.x;
  const int w  = t >> 6, l = t & 63;
  const int lr = l & 15, lh = l >> 4;
  const int wm = w >> 1, wn = w & 1;
  const int m0 = blockIdx.y * 128, n0 = blockIdx.x * 128;

  f32x4 acc[4][4];
#pragma unroll
  for (int mi = 0; mi < 4; ++mi)
#pragma unroll
    for (int ni = 0; ni < 4; ++ni) acc[mi][ni] = f32x4{0.f, 0.f, 0.f, 0.f};

  const int srow = l >> 2;
  const int scol = (l & 3) * 8;
  const u16* aP = A  + (size_t)(m0 + w * 16 + srow) * 768 + scol;
  const u16* bP = Bt + (size_t)(n0 + w * 16 + srow) * 768 + scol;
  char* asB = (char*)As + w * 1024;    // + p*8192 selects buffer
  char* bsB = (char*)Bs + w * 1024;

  // prologue: stage tile 0 into buf 0
  GLOAD_LDS16(aP,            asB);
  GLOAD_LDS16(aP + 64 * 768, asB + 4096);
  GLOAD_LDS16(bP,            bsB);
  GLOAD_LDS16(bP + 64 * 768, bsB + 4096);
  __syncthreads();   // drains vmcnt (compiler) + makes buf0 visible

  int p = 0;
  for (int kt = 0; kt < 23; ++kt) {
    {  // issue next tile into buf p^1 — in flight during compute
      const int ko = (kt + 1) * 32;
      const int bo = (p ^ 1) * 8192;
      GLOAD_LDS16(aP + ko,            asB + bo);
      GLOAD_LDS16(aP + ko + 64 * 768, asB + bo + 4096);
      GLOAD_LDS16(bP + ko,            bsB + bo);
      GLOAD_LDS16(bP + ko + 64 * 768, bsB + bo + 4096);
    }
    bf16x8 af[4], bfr[4];
#pragma unroll
    for (int mi = 0; mi < 4; ++mi)
      af[mi] = *(const bf16x8*)&As[p][wm * 64 + mi * 16 + lr][lh * 8];
#pragma unroll
    for (int ni = 0; ni < 4; ++ni)
      bfr[ni] = *(const bf16x8*)&Bs[p][wn * 64 + ni * 16 + lr][lh * 8];
#pragma unroll
    for (int mi = 0; mi < 4; ++mi)
#pragma unroll
      for (int ni = 0; ni < 4; ++ni)
        acc[mi][ni] = mfma16x16x32(af[mi], bfr[ni], acc[mi][ni]);
    __syncthreads();   // drains prefetch vmcnt + all readers past buf p
    p ^= 1;
  }
  {  // final tile (no prefetch)
    bf16x8 af[4], bfr[4];
#pragma unroll
    for (int mi = 0; mi < 4; ++mi)
      af[mi] = *(const bf16x8*)&As[p][wm * 64 + mi * 16 + lr][lh * 8];
#pragma unroll
    for (int ni = 0; ni < 4; ++ni)
      bfr[ni] = *(const bf16x8*)&Bs[p][wn * 64 + ni * 16 + lr][lh * 8];
#pragma unroll
    for (int mi = 0; mi < 4; ++mi)
#pragma unroll
      for (int ni = 0; ni < 4; ++ni)
        acc[mi][ni] = mfma16x16x32(af[mi], bfr[ni], acc[mi][ni]);
  }

  if (EPI == 0) {
#pragma unroll
    for (int mi = 0; mi < 4; ++mi)
#pragma unroll
      for (int ni = 0; ni < 4; ++ni) {
        const int col   = n0 + wn * 64 + ni * 16 + lr;
        const int which = col / 768;
        const int rem   = col - which * 768;
        const int h     = rem >> 6, d = rem & 63;
#pragma unroll
        for (int r = 0; r < 4; ++r) {
          const int m  = m0 + wm * 64 + mi * 16 + lh * 4 + r;
          const int bb = m >> 11, tt = m & 2047;   // T = 2048
          const u16 val = f2bf(acc[mi][ni][r]);
          if (which == 0)
            q_ws[(((size_t)(bb * Hc + h) * Tc + tt) << 6) + d] = val;
          else if (which == 1)
            k_ws[(((size_t)(bb * Hc + h) * Tc + tt) << 6) + d] = val;
          else   // V stored transposed: [bh][d][T]
            v_ws[(((size_t)((bb * Hc + h) * 64 + d)) << 11) + tt] = val;
        }
      }
  } else {
#pragma unroll
    for (int mi = 0; mi < 4; ++mi)
#pragma unroll
      for (int ni = 0; ni < 4; ++ni) {
        const int col = n0 + wn * 64 + ni * 16 + lr;
#pragma unroll
        for (int r = 0; r < 4; ++r) {
          const int m = m0 + wm * 64 + mi * 16 + lh * 4 + r;
          fout[(size_t)m * 768 + col] = acc[mi][ni][r];
        }
      }
  }
}

// ----------------------------------------------- sliding-window flash attention
// Q/K: [bh][T][64] bf16. Vt: [bh][64][T] bf16 (pre-transposed by gemm1).
// Barrier-free: every wave owns 16 query rows; Q/K/V fragments loaded DIRECTLY
// from global (L2-resident: K/V per head = 256 KB each). Only LDS use is the
// wave-private P re-layout tile. Out: [B][T][768] bf16.
__global__ __launch_bounds__(256) void swa_attn(const u16* __restrict__ Q,
                                                const u16* __restrict__ Kk,
                                                const u16* __restrict__ Vt,
                                                u16* __restrict__ Out) {
  __shared__ u16 Ps[4][16][72];   // per-wave P tile (16 q x 64 k), padded

  const int t  = threadIdx.x;
  const int w  = t >> 6, l = t & 63;
  const int lr = l & 15, lh = l >> 4;
  const int bh = blockIdx.y;
  const int q0 = blockIdx.x * 64 + w * 16;     // this wave's 16 query rows
  const size_t hb  = (size_t)bh * (Tc * 64);   // base for Q/K [bh][T][64]
  const size_t hbv = (size_t)bh * (64 * Tc);   // base for Vt [bh][64][T]

  // Q fragments, loaded once (rows q0+lr, k-chunks lh*8 and 32+lh*8)
  const bf16x8 qa0 = *(const bf16x8*)(Q + hb + (size_t)(q0 + lr) * 64 + lh * 8);
  const bf16x8 qa1 = *(const bf16x8*)(Q + hb + (size_t)(q0 + lr) * 64 + 32 + lh * 8);

  float m_r[4], l_r[4];
  f32x4 Oa[4];
#pragma unroll
  for (int r = 0; r < 4; ++r) { m_r[r] = -1e30f; l_r[r] = 0.f; }
#pragma unroll
  for (int n = 0; n < 4; ++n) Oa[n] = f32x4{0.f, 0.f, 0.f, 0.f};

  const int kb_lo = (q0 >= WINc) ? ((q0 - WINc) & ~63) : 0;
  const int kb_hi = q0 & ~63;                  // tile containing q0..q0+15
  for (int kb = kb_lo; kb <= kb_hi; kb += 64) {
    // ---- QK^T on K fragments straight from global
    f32x4 s[4];
#pragma unroll
    for (int sub = 0; sub < 4; ++sub) {
      const u16* kr = Kk + hb + (size_t)(kb + sub * 16 + lr) * 64;
      const bf16x8 kf0 = *(const bf16x8*)(kr + lh * 8);
      const bf16x8 kf1 = *(const bf16x8*)(kr + 32 + lh * 8);
      f32x4 z = f32x4{0.f, 0.f, 0.f, 0.f};
      z = mfma16x16x32(qa0, kf0, z);
      z = mfma16x16x32(qa1, kf1, z);
      s[sub] = z;
    }

    // ---- prefetch V fragments (independent of softmax; hides L2 latency)
    bf16x8 vf[2][4];
#pragma unroll
    for (int ks = 0; ks < 2; ++ks)
#pragma unroll
      for (int ni = 0; ni < 4; ++ni)
        vf[ks][ni] = *(const bf16x8*)(Vt + hbv + (size_t)(ni * 16 + lr) * Tc
                                      + kb + ks * 32 + lh * 8);

    // ---- mask + scale (allowed: qi-128 <= kj <= qi)
    const int qbase = q0 + lh * 4;
#pragma unroll
    for (int sub = 0; sub < 4; ++sub) {
      const int kj = kb + sub * 16 + lr;
#pragma unroll
      for (int r = 0; r < 4; ++r) {
        const int qi = qbase + r;
        const bool ok = (kj <= qi) && (kj + WINc >= qi);
        s[sub][r] = ok ? s[sub][r] * 0.125f : -1e30f;
      }
    }

    // ---- online softmax (row = reduce across lr group of 16 lanes)
    float mt[4];
#pragma unroll
    for (int r = 0; r < 4; ++r)
      mt[r] = fmaxf(fmaxf(s[0][r], s[1][r]), fmaxf(s[2][r], s[3][r]));
#pragma unroll
    for (int msk = 1; msk < 16; msk <<= 1)
#pragma unroll
      for (int r = 0; r < 4; ++r)
        mt[r] = fmaxf(mt[r], __shfl_xor(mt[r], msk, 64));

    float al[4];
#pragma unroll
    for (int r = 0; r < 4; ++r) {
      const float mn = fmaxf(m_r[r], mt[r]);
      al[r] = __expf(m_r[r] - mn);
      m_r[r] = mn;
    }

    float rs[4] = {0.f, 0.f, 0.f, 0.f};
#pragma unroll
    for (int sub = 0; sub < 4; ++sub)
#pragma unroll
      for (int r = 0; r < 4; ++r) {
        const float pv = __expf(s[sub][r] - m_r[r]);
        s[sub][r] = pv;
        rs[r] += pv;
      }
#pragma unroll
    for (int msk = 1; msk < 16; msk <<= 1)
#pragma unroll
      for (int r = 0; r < 4; ++r)
        rs[r] += __shfl_xor(rs[r], msk, 64);
#pragma unroll
    for (int r = 0; r < 4; ++r) l_r[r] = l_r[r] * al[r] + rs[r];

#pragma unroll
    for (int n = 0; n < 4; ++n)
#pragma unroll
      for (int r = 0; r < 4; ++r) Oa[n][r] *= al[r];

    // ---- P -> wave-private LDS (re-layout for PV A-operand); no barrier needed
#pragma unroll
    for (int sub = 0; sub < 4; ++sub)
#pragma unroll
      for (int r = 0; r < 4; ++r)
        Ps[w][lh * 4 + r][sub * 16 + lr] = f2bf(s[sub][r]);

    // ---- PV: O += P (16x64) * V (64x64)
#pragma unroll
    for (int ks = 0; ks < 2; ++ks) {
      const bf16x8 pa = *(const bf16x8*)&Ps[w][lr][ks * 32 + lh * 8];
#pragma unroll
      for (int ni = 0; ni < 4; ++ni)
        Oa[ni] = mfma16x16x32(pa, vf[ks][ni], Oa[ni]);
    }
  }

  // epilogue: write attn out [B][T][H*64] bf16
  const int bb = bh / Hc, h = bh - bb * Hc;
#pragma unroll
  for (int r = 0; r < 4; ++r) {
    const float inv = 1.f / l_r[r];
    const int ti = q0 + lh * 4 + r;
#pragma unroll
    for (int ni = 0; ni < 4; ++ni)
      Out[((size_t)(bb * Tc + ti)) * 768 + h * 64 + ni * 16 + lr] =
          f2bf(Oa[ni][r] * inv);
  }
}

// -----------------------------------------------------------------------------
extern "C" void kernel_launch(void* const* d_in, const int* in_sizes, int n_in,
                              void* d_out, int out_size, void* d_ws, size_t ws_size,
                              hipStream_t stream) {
  (void)in_sizes; (void)n_in; (void)out_size; (void)ws_size;
  const float* x    = (const float*)d_in[0];
  const float* Wqkv = (const float*)d_in[1];
  const float* Wout = (const float*)d_in[2];
  float* out = (float*)d_out;

  u16* ws    = (u16*)d_ws;
  u16* xb    = ws;                     // 6291456 elems (x as bf16)
  u16* wqkvT = xb + 6291456;           // 1769472
  u16* woutT = wqkvT + 1769472;        // 589824
  u16* qws   = woutT + 589824;         // 6291456
  u16* kws   = qws + 6291456;          // 6291456
  u16* vtws  = kws + 6291456;          // 6291456 (transposed layout)
  u16* aws   = xb;                     // attn out aliases xb (dead after gemm1)

  cvt_f32_to_bf16<<<6144, 256, 0, stream>>>(x, xb);
  transpose_cvt<<<dim3(36, 12), 256, 0, stream>>>(Wqkv, wqkvT, 768, 2304);
  transpose_cvt<<<dim3(12, 12), 256, 0, stream>>>(Wout, woutT, 768, 768);
  gemm_bt<0><<<dim3(18, 64), 256, 0, stream>>>(xb, wqkvT, qws, kws, vtws, nullptr);
  swa_attn<<<dim3(32, 48), 256, 0, stream>>>(qws, kws, vtws, aws);
  gemm_bt<1><<<dim3(6, 64), 256, 0, stream>>>(aws, woutT, nullptr, nullptr, nullptr, out);
}